// Round 10
// baseline (678.972 us; speedup 1.0000x reference)
//
#include <hip/hip_runtime.h>

// WaveNet residual stack — round 19.
//  r18 post-mortem: skip 116->100 µs (pipeline works) but wall flat — back-
//  solve shows epochs are ~105 µs each (~210 µs bucket, biggest). Cause by
//  construction: (a) bounds(256,2) -> as low as 2 blk/CU; (b) each layer ends
//  with syncthreads AFTER a global g-write => vmcnt(0) drain x10 on the
//  critical path with no co-resident work.
//  This round:
//   - epoch5: g-fragments buffered in regs (gbuf[5][2], 20 VGPR) and written
//     ONCE at kernel end. Algebra: slot offset i-sb = o0+p-(Lin-OSIZE) is
//     layer-independent (Dl cancels) -> one offset/mask for all 5 stores.
//     Per-layer barriers now drain LDS only. bounds(256,3).
//   - skip_gemm: bounds(256,6) (VGPR 44 << 85 cap, LDS 24 KB) — free width.
//  Singles/pack/schedule r18-verbatim.
// MFMA layouts (HW-verified): A[m=lane&15][k=quad*8+j], B[k=quad*8+j][n=lane&15],
// C/D col=lane&15 row=quad*4+reg.

#define NBATCH 16
#define C 64
#define SC 128
#define L0 8192
#define OSIZE 7682
#define TILE 64
#define SST 64

typedef __bf16 bf16x8 __attribute__((ext_vector_type(8)));
typedef __bf16 bf16x4 __attribute__((ext_vector_type(4)));
typedef float  f32x4  __attribute__((ext_vector_type(4)));

// ---- pre-pass: pack weights to bf16, k-contiguous MFMA A-layout ----
__global__ __launch_bounds__(256) void pack_weights(
    const float* __restrict__ Wd, const float* __restrict__ Wr,
    const float* __restrict__ Ws,
    __bf16* __restrict__ Wdm, __bf16* __restrict__ Wrm, __bf16* __restrict__ Wsm)
{
    int idx = blockIdx.x * 256 + threadIdx.x;
    if (idx < 131072) {                       // Wdm[ly][o][kp]: kp<64 tap0, else tap1
        int kp = idx & 127, o = (idx >> 7) & 63, ly = idx >> 13;
        int k = kp & 63, tap = kp >> 6;
        Wdm[idx] = (__bf16)Wd[(((ly * 64 + o) * 64 + k) << 1) + tap];
    } else if (idx < 196608) {                // Wrm[ly][o][k]
        int j = idx - 131072;
        Wrm[j] = (__bf16)Wr[j];
    } else if (idx < 327680) {                // Wsm[ly][s][k]
        int j = idx - 196608;
        Wsm[j] = (__bf16)Ws[j];
    }
}

// ---- fused 5-layer epoch (d=1,2,4,8,16), absolute right-tap coords ----
__global__ __launch_bounds__(256, 3) void wavenet_epoch5(
    const float* __restrict__ src, int Lin,    // stride L0
    float* __restrict__ dst,                   // stride L0, length Lin-31
    const __bf16* __restrict__ Wdm,            // 5 x [64][128] from base layer
    const __bf16* __restrict__ Wrm,            // 5 x [64][64]
    __bf16* __restrict__ gst, size_t slotHW)   // slots l = 0..4
{
    __shared__ __bf16 sxp[8][112][8];   // storage pp = p+16; pp<16 = zero pad
    __shared__ __bf16 sgp[8][96][8];    // gate out at p in [0,96)

    const int Lf = Lin - 31;
    const int n  = blockIdx.y;
    const int o0 = blockIdx.x * 64;     // own final cols [o0, o0+64) (left-aligned)
    if (o0 >= Lf) return;

    const int t    = threadIdx.x;
    const int lane = t & 63;
    const int wv   = t >> 6;
    const int q    = lane >> 4;
    const int nn   = lane & 15;
    const int kgw  = 2 * wv + (q >> 1);
    const int hf4  = (q & 1) * 4;

    // ---- initial stage: src cols [o0, o0+96) -> xs regs + bf16 LDS (pp=p+16) ----
    f32x4 xs[6];                            // ch = wv*16+q*4+r, p = nt*16+nn
    const float* base = src + (size_t)(n * C + wv * 16 + q * 4) * L0 + o0;
    #pragma unroll
    for (int nt = 0; nt < 6; ++nt) {
        int p = nt * 16 + nn;
        bool inb = (o0 + p) < Lin;
        #pragma unroll
        for (int r = 0; r < 4; ++r)
            xs[nt][r] = inb ? base[(size_t)r * L0 + p] : 0.f;
        bf16x4 v;
        #pragma unroll
        for (int r = 0; r < 4; ++r) v[r] = (__bf16)xs[nt][r];
        *(bf16x4*)(&sxp[0][0][0] + ((size_t)kgw * 112 + 16 + p) * 8 + hf4) = v;
    }
    {   // zero the left pad pp in [0,16)
        bf16x4 z = {(__bf16)0.f, (__bf16)0.f, (__bf16)0.f, (__bf16)0.f};
        *(bf16x4*)(&sxp[0][0][0] + ((size_t)kgw * 112 + nn) * 8 + hf4) = z;
    }
    __syncthreads();

    // deferred g-fragments: thread t owns (kg = t>>6 [+4j], p = 31 + (t&63))
    bf16x8 gbuf[5][2];
    const int gp  = 31 + (t & 63);          // own p range [31,95)
    const int gkg = t >> 6;

    #pragma unroll 1
    for (int l = 0; l < 5; ++l) {
        const int d = 1 << l;

        // ---- conv+gate: gate(p) = f(x(p-d), x(p))  [right-tap aligned] ----
        const __bf16* aw = Wdm + ((size_t)l * 64 + wv * 16 + nn) * 128 + q * 8;
        bf16x8 aW0 = *(const bf16x8*)(aw);        // tap0 (left), k 0..31
        bf16x8 aW1 = *(const bf16x8*)(aw + 32);   // tap0, k 32..63
        bf16x8 aW2 = *(const bf16x8*)(aw + 64);   // tap1 (right), k 0..31
        bf16x8 aW3 = *(const bf16x8*)(aw + 96);   // tap1, k 32..63
        #pragma unroll
        for (int nt = 0; nt < 6; ++nt) {
            int p = nt * 16 + nn;
            f32x4 acc = {0.f, 0.f, 0.f, 0.f};
            acc = __builtin_amdgcn_mfma_f32_16x16x32_bf16(aW0,
                    *(const bf16x8*)(&sxp[0][0][0] + ((size_t)(q    ) * 112 + 16 + p - d) * 8), acc, 0, 0, 0);
            acc = __builtin_amdgcn_mfma_f32_16x16x32_bf16(aW1,
                    *(const bf16x8*)(&sxp[0][0][0] + ((size_t)(4 + q) * 112 + 16 + p - d) * 8), acc, 0, 0, 0);
            acc = __builtin_amdgcn_mfma_f32_16x16x32_bf16(aW2,
                    *(const bf16x8*)(&sxp[0][0][0] + ((size_t)(q    ) * 112 + 16 + p    ) * 8), acc, 0, 0, 0);
            acc = __builtin_amdgcn_mfma_f32_16x16x32_bf16(aW3,
                    *(const bf16x8*)(&sxp[0][0][0] + ((size_t)(4 + q) * 112 + 16 + p    ) * 8), acc, 0, 0, 0);
            bf16x4 gv;
            #pragma unroll
            for (int r = 0; r < 4; ++r) {
                float y = fminf(fmaxf(acc[r], -20.f), 20.f);
                float u = __expf(y);
                gv[r] = (__bf16)(u * (u - 1.f) / fmaf(u, u, 1.f));
            }
            *(bf16x4*)(&sgp[0][0][0] + ((size_t)kgw * 96 + p) * 8 + hf4) = gv;
        }
        __syncthreads();          // sgp visible; conv reads of sxp done

        // ---- res: xs(p) = Wr@g(p) + xs(p); refresh sxp; capture g to regs ----
        const __bf16* ar = Wrm + ((size_t)l * 64 + wv * 16 + nn) * 64 + q * 8;
        bf16x8 aR0 = *(const bf16x8*)ar;
        bf16x8 aR1 = *(const bf16x8*)(ar + 32);
        #pragma unroll
        for (int nt = 0; nt < 6; ++nt) {
            int p = nt * 16 + nn;
            bf16x8 b0 = *(const bf16x8*)(&sgp[0][0][0] + ((size_t)(q    ) * 96 + p) * 8);
            bf16x8 b1 = *(const bf16x8*)(&sgp[0][0][0] + ((size_t)(4 + q) * 96 + p) * 8);
            xs[nt] = __builtin_amdgcn_mfma_f32_16x16x32_bf16(aR1, b1,
                     __builtin_amdgcn_mfma_f32_16x16x32_bf16(aR0, b0, xs[nt], 0, 0, 0),
                     0, 0, 0);
            bf16x4 v;
            #pragma unroll
            for (int r = 0; r < 4; ++r) v[r] = (__bf16)xs[nt][r];
            *(bf16x4*)(&sxp[0][0][0] + ((size_t)kgw * 112 + 16 + p) * 8 + hf4) = v;
        }
        gbuf[l][0] = *(const bf16x8*)(&sgp[0][0][0] + ((size_t)gkg       * 96 + gp) * 8);
        gbuf[l][1] = *(const bf16x8*)(&sgp[0][0][0] + ((size_t)(gkg + 4) * 96 + gp) * 8);
        __syncthreads();          // sxp refresh visible; sgp reads done (LDS-only drain)
    }

    // ---- deferred g writes: offset i-sb = o0+p-(Lin-OSIZE), layer-independent ----
    {
        const int off = o0 + gp - (Lin - OSIZE);
        if (off >= 0 && off < OSIZE) {
            #pragma unroll
            for (int l = 0; l < 5; ++l) {
                __bf16* gsl = gst + (size_t)l * slotHW;
                *(bf16x8*)(gsl + (((size_t)n * 8 + gkg    ) * OSIZE + off) * 8) = gbuf[l][0];
                *(bf16x8*)(gsl + (((size_t)n * 8 + gkg + 4) * OSIZE + off) * 8) = gbuf[l][1];
            }
        }
    }

    // ---- write epoch-final stream: dst col i = o0 + p - 31, p in [31,95) ----
    #pragma unroll
    for (int nt = 1; nt < 6; ++nt) {
        int p = nt * 16 + nn;
        if (p >= 31 && p < 95) {
            int i = o0 + p - 31;
            if (i < Lf) {
                #pragma unroll
                for (int r = 0; r < 4; ++r)
                    dst[(size_t)(n * C + wv * 16 + q * 4 + r) * L0 + i] = xs[nt][r];
            }
        }
    }
}

// ---- per-layer: conv(MFMA) + gate + res(MFMA) + g window out (r9-verbatim) ----
__global__ __launch_bounds__(256) void wavenet_layer_mfma(
    const float* __restrict__ src, int src_stride, int Lin,
    float* __restrict__ dst, int dst_stride,
    const __bf16* __restrict__ Wdm,   // [64][128]
    const __bf16* __restrict__ Wrm,   // [64][64]
    __bf16* __restrict__ gout,        // [NBATCH][8][OSIZE][8] this layer's slot
    int d)
{
    extern __shared__ char smem_raw[];
    const int W    = TILE + d;
    const int Lout = Lin - d;
    const int n  = blockIdx.y;
    const int l0 = blockIdx.x * TILE;
    if (l0 >= Lout) return;
    const int np = min(TILE, Lout - l0);

    __bf16* sxp  = (__bf16*)smem_raw;                          // [8][W][8] k-packed
    float*  sres = (float*)(smem_raw + (size_t)8 * W * 8 * 2); // [64][65] fp32
    __bf16* sgp  = (__bf16*)(sres + 64 * 65);                  // [8][64][8] k-packed

    const int t    = threadIdx.x;
    const int lane = t & 63;
    const int wv   = t >> 6;
    const int q    = lane >> 4;
    const int nn   = lane & 15;

    for (int item = t; item < 8 * W; item += 256) {
        int kg = item / W;
        int p  = item % W;
        bool inb = (l0 + p) < Lin;
        const float* col = src + (size_t)(n * C + kg * 8) * src_stride + l0 + p;
        float v[8];
        #pragma unroll
        for (int j = 0; j < 8; ++j) v[j] = inb ? col[(size_t)j * src_stride] : 0.f;
        bf16x8 bv;
        #pragma unroll
        for (int j = 0; j < 8; ++j) bv[j] = (__bf16)v[j];
        *(bf16x8*)(sxp + ((size_t)kg * W + p) * 8) = bv;
        int pr = p - d;
        if (pr >= 0 && pr < TILE) {
            #pragma unroll
            for (int j = 0; j < 8; ++j) sres[(kg * 8 + j) * 65 + pr] = v[j];
        }
    }
    __syncthreads();

    const __bf16* arow = Wdm + (size_t)(wv * 16 + nn) * 128 + q * 8;
    bf16x8 aW[4];
    #pragma unroll
    for (int ks = 0; ks < 4; ++ks) aW[ks] = *(const bf16x8*)(arow + ks * 32);

    #pragma unroll
    for (int nt = 0; nt < 4; ++nt) {
        int p0 = nt * 16;
        f32x4 acc = {0.f, 0.f, 0.f, 0.f};
        acc = __builtin_amdgcn_mfma_f32_16x16x32_bf16(aW[0],
                *(const bf16x8*)(sxp + ((size_t)(q    ) * W + p0 + nn    ) * 8), acc, 0, 0, 0);
        acc = __builtin_amdgcn_mfma_f32_16x16x32_bf16(aW[1],
                *(const bf16x8*)(sxp + ((size_t)(4 + q) * W + p0 + nn    ) * 8), acc, 0, 0, 0);
        acc = __builtin_amdgcn_mfma_f32_16x16x32_bf16(aW[2],
                *(const bf16x8*)(sxp + ((size_t)(q    ) * W + p0 + nn + d) * 8), acc, 0, 0, 0);
        acc = __builtin_amdgcn_mfma_f32_16x16x32_bf16(aW[3],
                *(const bf16x8*)(sxp + ((size_t)(4 + q) * W + p0 + nn + d) * 8), acc, 0, 0, 0);
        bf16x4 gv;
        #pragma unroll
        for (int r = 0; r < 4; ++r) {
            float y = fminf(fmaxf(acc[r], -20.f), 20.f);
            float u = __expf(y);
            gv[r] = (__bf16)(u * (u - 1.f) / fmaf(u, u, 1.f));
        }
        *(bf16x4*)(sgp + ((size_t)(2 * wv + (q >> 1)) * 64 + p0 + nn) * 8 + (q & 1) * 4) = gv;
    }
    __syncthreads();

    const __bf16* rrow = Wrm + (size_t)(wv * 16 + nn) * 64 + q * 8;
    bf16x8 aR0 = *(const bf16x8*)rrow;
    bf16x8 aR1 = *(const bf16x8*)(rrow + 32);
    #pragma unroll
    for (int nt = 0; nt < 4; ++nt) {
        int p0 = nt * 16;
        f32x4 acc = {0.f, 0.f, 0.f, 0.f};
        acc = __builtin_amdgcn_mfma_f32_16x16x32_bf16(aR0,
                *(const bf16x8*)(sgp + ((size_t)(q    ) * 64 + p0 + nn) * 8), acc, 0, 0, 0);
        acc = __builtin_amdgcn_mfma_f32_16x16x32_bf16(aR1,
                *(const bf16x8*)(sgp + ((size_t)(4 + q) * 64 + p0 + nn) * 8), acc, 0, 0, 0);
        if (p0 + nn < np) {
            #pragma unroll
            for (int r = 0; r < 4; ++r) {
                int ch = wv * 16 + q * 4 + r;
                dst[(size_t)(n * C + ch) * dst_stride + l0 + p0 + nn]
                    = acc[r] + sres[ch * 65 + p0 + nn];
            }
        }
    }

    const int sbase = Lout - OSIZE;
    for (int item = t; item < 8 * TILE; item += 256) {
        int p  = item & 63;
        int kg = item >> 6;
        int l  = l0 + p;
        if (l >= sbase && l < Lout) {
            *(bf16x8*)(gout + (((size_t)n * 8 + kg) * OSIZE + (l - sbase)) * 8)
                = *(const bf16x8*)(sgp + ((size_t)kg * 64 + p) * 8);
        }
    }
}

// ---- skip = sum over G layers of Ws@g ; ST=64, ring-3, reg-pipelined A ----
__global__ __launch_bounds__(256, 6) void skip_gemm(
    const __bf16* __restrict__ g,     // [G][NBATCH][8][OSIZE][8]
    const __bf16* __restrict__ Wsm,   // [16][128][64]
    float* __restrict__ skip,         // [NBATCH][128][OSIZE]
    int G, int lybase, int init)
{
    __shared__ __bf16 Bb[3][8][SST][8];   // 24 KB ring
    const int n  = blockIdx.y;
    const int l0 = blockIdx.x * SST;
    const int t  = threadIdx.x;
    const int lane = t & 63;
    const int wv   = __builtin_amdgcn_readfirstlane(t >> 6);
    const int q = lane >> 4, nn = lane & 15;

    f32x4 acc[2][4];
    #pragma unroll
    for (int mt = 0; mt < 2; ++mt)
        #pragma unroll
        for (int nt = 0; nt < 4; ++nt) acc[mt][nt] = (f32x4){0.f, 0.f, 0.f, 0.f};

    // stage K-tile gi (8 KB/block; 2 global_load_lds x 16B per wave)
    auto stage = [&](int buf, int gi) {
        const __bf16* gl = g + ((size_t)gi * NBATCH + n) * (size_t)8 * OSIZE * 8;
        #pragma unroll
        for (int j = 0; j < 2; ++j) {
            int kg = 2 * wv + j;
            const __bf16* srcp = gl + ((size_t)kg * OSIZE + l0) * 8 + (size_t)lane * 8;
            __builtin_amdgcn_global_load_lds(
                (const __attribute__((address_space(1))) void*)srcp,
                (__attribute__((address_space(3))) void*)&Bb[buf][kg][0][0],
                16, 0, 0);
        }
    };
    auto loadA = [&](int gi, bf16x8* A) {
        const __bf16* Wl = Wsm + (size_t)(lybase + gi) * SC * 64;
        A[0] = *(const bf16x8*)(Wl + (size_t)(wv * 32 +      nn) * 64 +      q * 8);
        A[1] = *(const bf16x8*)(Wl + (size_t)(wv * 32 +      nn) * 64 + 32 + q * 8);
        A[2] = *(const bf16x8*)(Wl + (size_t)(wv * 32 + 16 + nn) * 64 +      q * 8);
        A[3] = *(const bf16x8*)(Wl + (size_t)(wv * 32 + 16 + nn) * 64 + 32 + q * 8);
    };
    auto mfma16 = [&](const bf16x8* A, int cur) {
        #pragma unroll
        for (int ks = 0; ks < 2; ++ks) {
            #pragma unroll
            for (int nt = 0; nt < 4; ++nt) {
                bf16x8 b = *(const bf16x8*)&Bb[cur][ks * 4 + q][nt * 16 + nn][0];
                acc[0][nt] = __builtin_amdgcn_mfma_f32_16x16x32_bf16(
                                 A[ks], b, acc[0][nt], 0, 0, 0);
                acc[1][nt] = __builtin_amdgcn_mfma_f32_16x16x32_bf16(
                                 A[2 + ks], b, acc[1][nt], 0, 0, 0);
            }
        }
    };

    bf16x8 aA[4], aB[4];
    // prologue issue order: stage0(2), A0(4), stage1(2)
    stage(0, 0);
    loadA(0, aA);
    stage(1, G > 1 ? 1 : 0);

    for (int gi = 0; gi < G; gi += 2) {
        // ---- even half: tile gi (regs aA); prefetch A(gi+1)->aB, stage gi+2 ----
        asm volatile("s_waitcnt vmcnt(6)" ::: "memory");   // tile gi landed
        __builtin_amdgcn_s_barrier();
        __builtin_amdgcn_sched_barrier(0);
        loadA(gi + 1 < G ? gi + 1 : gi, aB);               // issued before stage
        stage((gi + 2) % 3, gi + 2 < G ? gi + 2 : G - 1);
        __builtin_amdgcn_sched_barrier(0);
        mfma16(aA, gi % 3);                                // A-wait leaves stages in flight
        __builtin_amdgcn_s_barrier();

        // ---- odd half: tile gi+1 (regs aB); prefetch A(gi+2)->aA, stage gi+3 ----
        asm volatile("s_waitcnt vmcnt(6)" ::: "memory");   // tile gi+1 landed
        __builtin_amdgcn_s_barrier();
        __builtin_amdgcn_sched_barrier(0);
        loadA(gi + 2 < G ? gi + 2 : gi, aA);
        stage((gi + 3) % 3, gi + 3 < G ? gi + 3 : G - 1);
        __builtin_amdgcn_sched_barrier(0);
        mfma16(aB, (gi + 1) % 3);
        __builtin_amdgcn_s_barrier();
    }

    #pragma unroll
    for (int mt = 0; mt < 2; ++mt)
        #pragma unroll
        for (int nt = 0; nt < 4; ++nt) {
            int p = l0 + nt * 16 + nn;
            if (p < OSIZE) {
                #pragma unroll
                for (int r = 0; r < 4; ++r) {
                    int s = wv * 32 + mt * 16 + q * 4 + r;
                    size_t idx = ((size_t)n * SC + s) * OSIZE + p;
                    float v = acc[mt][nt][r];
                    skip[idx] = init ? v : (skip[idx] + v);
                }
            }
        }
}

extern "C" void kernel_launch(void* const* d_in, const int* in_sizes, int n_in,
                              void* d_out, int out_size, void* d_ws, size_t ws_size,
                              hipStream_t stream) {
    const float* x      = (const float*)d_in[0];
    const float* W_dil  = (const float*)d_in[1];
    const float* W_res  = (const float*)d_in[2];
    const float* W_skip = (const float*)d_in[3];

    float* out  = (float*)d_out;                        // [16][64][7682]
    float* skip = out + (size_t)NBATCH * C * OSIZE;     // [16][128][7682]

    float*  bufA = (float*)d_ws;
    float*  bufB = bufA + (size_t)NBATCH * C * L0;
    __bf16* Wdm  = (__bf16*)(bufB + (size_t)NBATCH * C * L0);
    __bf16* Wrm  = Wdm + 16 * 64 * 128;
    __bf16* Wsm  = Wrm + 16 * 64 * 64;
    __bf16* gst  = Wsm + 16 * 128 * 64;

    const size_t slotHW = (size_t)NBATCH * 8 * OSIZE * 8;   // halfwords per slot
    const int G = 8;

    pack_weights<<<1280, 256, 0, stream>>>(W_dil, W_res, W_skip, Wdm, Wrm, Wsm);

    // ---- stack A: fused epoch layers 0-4 (d=1..16) ----
    {
        int Lin = L0, Lf = Lin - 31;                    // 8161
        dim3 grid((Lf + 63) / 64, NBATCH);
        wavenet_epoch5<<<grid, 256, 0, stream>>>(
            x, Lin, bufA, Wdm, Wrm, gst, slotHW);
    }
    // singles: layers 5,6,7 (d=32,64,128)
    {
        const float* src = bufA; float* dsts[3] = {bufB, bufA, bufB};
        int Lin = L0 - 31;
        for (int k = 0; k < 3; ++k) {
            int i = 5 + k, d = 32 << k, Lout = Lin - d;
            int W = TILE + d;
            size_t smem = (size_t)128 * W + 64 * 65 * 4 + 8 * 64 * 8 * 2;
            dim3 grid((Lout + TILE - 1) / TILE, NBATCH);
            wavenet_layer_mfma<<<grid, 256, smem, stream>>>(
                src, L0, Lin, dsts[k], L0,
                Wdm + (size_t)i * 64 * 128, Wrm + (size_t)i * 64 * 64,
                gst + (size_t)(i % G) * slotHW, d);
            src = dsts[k]; Lin = Lout;
        }
    }
    {   // skip over layers 0..7
        dim3 sgrid((OSIZE + SST - 1) / SST, NBATCH);
        skip_gemm<<<sgrid, 256, 0, stream>>>(gst, Wsm, skip, G, 0, 1);
    }

    // ---- stack B: fused epoch layers 8-12 ----
    {
        int Lin = L0 - 255;                              // 7937
        int Lf = Lin - 31;                               // 7906
        dim3 grid((Lf + 63) / 64, NBATCH);
        wavenet_epoch5<<<grid, 256, 0, stream>>>(
            bufB, Lin, bufA,
            Wdm + (size_t)8 * 64 * 128, Wrm + (size_t)8 * 64 * 64,
            gst, slotHW);                                // slots (8..12)%8 = 0..4
    }
    // singles: layers 13,14 (-> bufs), 15 (d=128 -> out, stride OSIZE)
    {
        const float* src = bufA;
        int Lin = L0 - 255 - 31;                         // 7906
        float* dsts[3] = {bufB, bufA, out};
        int strides[3] = {L0, L0, OSIZE};
        for (int k = 0; k < 3; ++k) {
            int i = 13 + k, d = 32 << k, Lout = Lin - d;
            int W = TILE + d;
            size_t smem = (size_t)128 * W + 64 * 65 * 4 + 8 * 64 * 8 * 2;
            dim3 grid((Lout + TILE - 1) / TILE, NBATCH);
            wavenet_layer_mfma<<<grid, 256, smem, stream>>>(
                src, L0, Lin, dsts[k], strides[k],
                Wdm + (size_t)i * 64 * 128, Wrm + (size_t)i * 64 * 64,
                gst + (size_t)(i % G) * slotHW, d);
            src = dsts[k]; Lin = Lout;
        }
    }
    {   // skip over layers 8..15
        dim3 sgrid((OSIZE + SST - 1) / SST, NBATCH);
        skip_gemm<<<sgrid, 256, 0, stream>>>(gst, Wsm, skip, G, 8, 0);
    }
}

// Round 11
// 546.431 us; speedup vs baseline: 1.2426x; 1.2426x over previous
//
#include <hip/hip_runtime.h>

// WaveNet residual stack — round 20: revert r19, isolate two safe deltas.
//  r19 post-mortem: (a) skip (256,6) raised BW 2.0->2.28 TB/s but write
//  working-set (192 blk x 32KB) blew the 4MB L2 -> WRITE 83->167 MB, net
//  134 µs. Occupancy trades against L2 write locality: keep (256,4).
//  (b) epoch gbuf+bounds(256,3) likely spilled (+40 VGPR under a 170 cap).
//  This round = r18 verbatim EXCEPT:
//   1. epoch bounds (256,2)->(256,3) alone (no gbuf): r18 demand ~120-150
//      regs fits the ~170 cap; +50% waves for a barrier-latency kernel.
//   2. skip epilogue stores row-major (mt->r->nt): 4x64B segments of each
//      row issue back-to-back -> full 256B write-combine runs, attacks the
//      residual 1.33x write amplification.
// MFMA layouts (HW-verified): A[m=lane&15][k=quad*8+j], B[k=quad*8+j][n=lane&15],
// C/D col=lane&15 row=quad*4+reg.

#define NBATCH 16
#define C 64
#define SC 128
#define L0 8192
#define OSIZE 7682
#define TILE 64
#define SST 64

typedef __bf16 bf16x8 __attribute__((ext_vector_type(8)));
typedef __bf16 bf16x4 __attribute__((ext_vector_type(4)));
typedef float  f32x4  __attribute__((ext_vector_type(4)));

// ---- pre-pass: pack weights to bf16, k-contiguous MFMA A-layout ----
__global__ __launch_bounds__(256) void pack_weights(
    const float* __restrict__ Wd, const float* __restrict__ Wr,
    const float* __restrict__ Ws,
    __bf16* __restrict__ Wdm, __bf16* __restrict__ Wrm, __bf16* __restrict__ Wsm)
{
    int idx = blockIdx.x * 256 + threadIdx.x;
    if (idx < 131072) {                       // Wdm[ly][o][kp]: kp<64 tap0, else tap1
        int kp = idx & 127, o = (idx >> 7) & 63, ly = idx >> 13;
        int k = kp & 63, tap = kp >> 6;
        Wdm[idx] = (__bf16)Wd[(((ly * 64 + o) * 64 + k) << 1) + tap];
    } else if (idx < 196608) {                // Wrm[ly][o][k]
        int j = idx - 131072;
        Wrm[j] = (__bf16)Wr[j];
    } else if (idx < 327680) {                // Wsm[ly][s][k]
        int j = idx - 196608;
        Wsm[j] = (__bf16)Ws[j];
    }
}

// ---- fused 5-layer epoch (d=1,2,4,8,16), absolute right-tap coords ----
__global__ __launch_bounds__(256, 3) void wavenet_epoch5(
    const float* __restrict__ src, int Lin,    // stride L0
    float* __restrict__ dst,                   // stride L0, length Lin-31
    const __bf16* __restrict__ Wdm,            // 5 x [64][128] from base layer
    const __bf16* __restrict__ Wrm,            // 5 x [64][64]
    __bf16* __restrict__ gst, size_t slotHW)   // slots l = 0..4
{
    __shared__ __bf16 sxp[8][112][8];   // storage pp = p+16; pp<16 = zero pad
    __shared__ __bf16 sgp[8][96][8];    // gate out at p in [0,96)

    const int Lf = Lin - 31;
    const int n  = blockIdx.y;
    const int o0 = blockIdx.x * 64;     // own final cols [o0, o0+64) (left-aligned)
    if (o0 >= Lf) return;

    const int t    = threadIdx.x;
    const int lane = t & 63;
    const int wv   = t >> 6;
    const int q    = lane >> 4;
    const int nn   = lane & 15;
    const int kgw  = 2 * wv + (q >> 1);
    const int hf4  = (q & 1) * 4;

    // ---- initial stage: src cols [o0, o0+96) -> xs regs + bf16 LDS (pp=p+16) ----
    f32x4 xs[6];                            // ch = wv*16+q*4+r, p = nt*16+nn
    const float* base = src + (size_t)(n * C + wv * 16 + q * 4) * L0 + o0;
    #pragma unroll
    for (int nt = 0; nt < 6; ++nt) {
        int p = nt * 16 + nn;
        bool inb = (o0 + p) < Lin;
        #pragma unroll
        for (int r = 0; r < 4; ++r)
            xs[nt][r] = inb ? base[(size_t)r * L0 + p] : 0.f;
        bf16x4 v;
        #pragma unroll
        for (int r = 0; r < 4; ++r) v[r] = (__bf16)xs[nt][r];
        *(bf16x4*)(&sxp[0][0][0] + ((size_t)kgw * 112 + 16 + p) * 8 + hf4) = v;
    }
    {   // zero the left pad pp in [0,16)
        bf16x4 z = {(__bf16)0.f, (__bf16)0.f, (__bf16)0.f, (__bf16)0.f};
        *(bf16x4*)(&sxp[0][0][0] + ((size_t)kgw * 112 + nn) * 8 + hf4) = z;
    }
    __syncthreads();

    #pragma unroll 1
    for (int l = 0; l < 5; ++l) {
        const int d = 1 << l;

        // ---- conv+gate: gate(p) = f(x(p-d), x(p))  [right-tap aligned] ----
        const __bf16* aw = Wdm + ((size_t)l * 64 + wv * 16 + nn) * 128 + q * 8;
        bf16x8 aW0 = *(const bf16x8*)(aw);        // tap0 (left), k 0..31
        bf16x8 aW1 = *(const bf16x8*)(aw + 32);   // tap0, k 32..63
        bf16x8 aW2 = *(const bf16x8*)(aw + 64);   // tap1 (right), k 0..31
        bf16x8 aW3 = *(const bf16x8*)(aw + 96);   // tap1, k 32..63
        #pragma unroll
        for (int nt = 0; nt < 6; ++nt) {
            int p = nt * 16 + nn;
            f32x4 acc = {0.f, 0.f, 0.f, 0.f};
            acc = __builtin_amdgcn_mfma_f32_16x16x32_bf16(aW0,
                    *(const bf16x8*)(&sxp[0][0][0] + ((size_t)(q    ) * 112 + 16 + p - d) * 8), acc, 0, 0, 0);
            acc = __builtin_amdgcn_mfma_f32_16x16x32_bf16(aW1,
                    *(const bf16x8*)(&sxp[0][0][0] + ((size_t)(4 + q) * 112 + 16 + p - d) * 8), acc, 0, 0, 0);
            acc = __builtin_amdgcn_mfma_f32_16x16x32_bf16(aW2,
                    *(const bf16x8*)(&sxp[0][0][0] + ((size_t)(q    ) * 112 + 16 + p    ) * 8), acc, 0, 0, 0);
            acc = __builtin_amdgcn_mfma_f32_16x16x32_bf16(aW3,
                    *(const bf16x8*)(&sxp[0][0][0] + ((size_t)(4 + q) * 112 + 16 + p    ) * 8), acc, 0, 0, 0);
            bf16x4 gv;
            #pragma unroll
            for (int r = 0; r < 4; ++r) {
                float y = fminf(fmaxf(acc[r], -20.f), 20.f);
                float u = __expf(y);
                gv[r] = (__bf16)(u * (u - 1.f) / fmaf(u, u, 1.f));
            }
            *(bf16x4*)(&sgp[0][0][0] + ((size_t)kgw * 96 + p) * 8 + hf4) = gv;
        }
        __syncthreads();          // sgp visible; conv reads of sxp done

        // ---- res: xs(p) = Wr@g(p) + xs(p)  [same absolute col] ----
        const __bf16* ar = Wrm + ((size_t)l * 64 + wv * 16 + nn) * 64 + q * 8;
        bf16x8 aR0 = *(const bf16x8*)ar;
        bf16x8 aR1 = *(const bf16x8*)(ar + 32);
        #pragma unroll
        for (int nt = 0; nt < 6; ++nt) {
            int p = nt * 16 + nn;
            bf16x8 b0 = *(const bf16x8*)(&sgp[0][0][0] + ((size_t)(q    ) * 96 + p) * 8);
            bf16x8 b1 = *(const bf16x8*)(&sgp[0][0][0] + ((size_t)(4 + q) * 96 + p) * 8);
            xs[nt] = __builtin_amdgcn_mfma_f32_16x16x32_bf16(aR1, b1,
                     __builtin_amdgcn_mfma_f32_16x16x32_bf16(aR0, b0, xs[nt], 0, 0, 0),
                     0, 0, 0);
            bf16x4 v;
            #pragma unroll
            for (int r = 0; r < 4; ++r) v[r] = (__bf16)xs[nt][r];
            *(bf16x4*)(&sxp[0][0][0] + ((size_t)kgw * 112 + 16 + p) * 8 + hf4) = v;
        }

        // ---- g window write: left index i = o0+p-Dl, window [Ll-OSIZE, Ll) ----
        const int Dl = (2 << l) - 1;           // cumulative dilation through l
        const int Ll = Lin - Dl;
        const int sb = Ll - OSIZE;             // >= 224 for all stacks/layers
        __bf16* gsl = gst + (size_t)l * slotHW;
        for (int item = t; item < 8 * 64; item += 256) {
            int p  = 31 + (item & 63);         // own range [31,95)
            int kg = item >> 6;
            int i  = o0 + p - Dl;
            if (i >= sb && i < Ll) {
                *(bf16x8*)(gsl + (((size_t)n * 8 + kg) * OSIZE + (i - sb)) * 8)
                    = *(const bf16x8*)(&sgp[0][0][0] + ((size_t)kg * 96 + p) * 8);
            }
        }
        __syncthreads();          // sxp refresh visible; sgp reads done
    }

    // ---- write epoch-final stream: dst col i = o0 + p - 31, p in [31,95) ----
    #pragma unroll
    for (int nt = 1; nt < 6; ++nt) {
        int p = nt * 16 + nn;
        if (p >= 31 && p < 95) {
            int i = o0 + p - 31;
            if (i < Lf) {
                #pragma unroll
                for (int r = 0; r < 4; ++r)
                    dst[(size_t)(n * C + wv * 16 + q * 4 + r) * L0 + i] = xs[nt][r];
            }
        }
    }
}

// ---- per-layer: conv(MFMA) + gate + res(MFMA) + g window out (r9-verbatim) ----
__global__ __launch_bounds__(256) void wavenet_layer_mfma(
    const float* __restrict__ src, int src_stride, int Lin,
    float* __restrict__ dst, int dst_stride,
    const __bf16* __restrict__ Wdm,   // [64][128]
    const __bf16* __restrict__ Wrm,   // [64][64]
    __bf16* __restrict__ gout,        // [NBATCH][8][OSIZE][8] this layer's slot
    int d)
{
    extern __shared__ char smem_raw[];
    const int W    = TILE + d;
    const int Lout = Lin - d;
    const int n  = blockIdx.y;
    const int l0 = blockIdx.x * TILE;
    if (l0 >= Lout) return;
    const int np = min(TILE, Lout - l0);

    __bf16* sxp  = (__bf16*)smem_raw;                          // [8][W][8] k-packed
    float*  sres = (float*)(smem_raw + (size_t)8 * W * 8 * 2); // [64][65] fp32
    __bf16* sgp  = (__bf16*)(sres + 64 * 65);                  // [8][64][8] k-packed

    const int t    = threadIdx.x;
    const int lane = t & 63;
    const int wv   = t >> 6;
    const int q    = lane >> 4;
    const int nn   = lane & 15;

    for (int item = t; item < 8 * W; item += 256) {
        int kg = item / W;
        int p  = item % W;
        bool inb = (l0 + p) < Lin;
        const float* col = src + (size_t)(n * C + kg * 8) * src_stride + l0 + p;
        float v[8];
        #pragma unroll
        for (int j = 0; j < 8; ++j) v[j] = inb ? col[(size_t)j * src_stride] : 0.f;
        bf16x8 bv;
        #pragma unroll
        for (int j = 0; j < 8; ++j) bv[j] = (__bf16)v[j];
        *(bf16x8*)(sxp + ((size_t)kg * W + p) * 8) = bv;
        int pr = p - d;
        if (pr >= 0 && pr < TILE) {
            #pragma unroll
            for (int j = 0; j < 8; ++j) sres[(kg * 8 + j) * 65 + pr] = v[j];
        }
    }
    __syncthreads();

    const __bf16* arow = Wdm + (size_t)(wv * 16 + nn) * 128 + q * 8;
    bf16x8 aW[4];
    #pragma unroll
    for (int ks = 0; ks < 4; ++ks) aW[ks] = *(const bf16x8*)(arow + ks * 32);

    #pragma unroll
    for (int nt = 0; nt < 4; ++nt) {
        int p0 = nt * 16;
        f32x4 acc = {0.f, 0.f, 0.f, 0.f};
        acc = __builtin_amdgcn_mfma_f32_16x16x32_bf16(aW[0],
                *(const bf16x8*)(sxp + ((size_t)(q    ) * W + p0 + nn    ) * 8), acc, 0, 0, 0);
        acc = __builtin_amdgcn_mfma_f32_16x16x32_bf16(aW[1],
                *(const bf16x8*)(sxp + ((size_t)(4 + q) * W + p0 + nn    ) * 8), acc, 0, 0, 0);
        acc = __builtin_amdgcn_mfma_f32_16x16x32_bf16(aW[2],
                *(const bf16x8*)(sxp + ((size_t)(q    ) * W + p0 + nn + d) * 8), acc, 0, 0, 0);
        acc = __builtin_amdgcn_mfma_f32_16x16x32_bf16(aW[3],
                *(const bf16x8*)(sxp + ((size_t)(4 + q) * W + p0 + nn + d) * 8), acc, 0, 0, 0);
        bf16x4 gv;
        #pragma unroll
        for (int r = 0; r < 4; ++r) {
            float y = fminf(fmaxf(acc[r], -20.f), 20.f);
            float u = __expf(y);
            gv[r] = (__bf16)(u * (u - 1.f) / fmaf(u, u, 1.f));
        }
        *(bf16x4*)(sgp + ((size_t)(2 * wv + (q >> 1)) * 64 + p0 + nn) * 8 + (q & 1) * 4) = gv;
    }
    __syncthreads();

    const __bf16* rrow = Wrm + (size_t)(wv * 16 + nn) * 64 + q * 8;
    bf16x8 aR0 = *(const bf16x8*)rrow;
    bf16x8 aR1 = *(const bf16x8*)(rrow + 32);
    #pragma unroll
    for (int nt = 0; nt < 4; ++nt) {
        int p0 = nt * 16;
        f32x4 acc = {0.f, 0.f, 0.f, 0.f};
        acc = __builtin_amdgcn_mfma_f32_16x16x32_bf16(aR0,
                *(const bf16x8*)(sgp + ((size_t)(q    ) * 64 + p0 + nn) * 8), acc, 0, 0, 0);
        acc = __builtin_amdgcn_mfma_f32_16x16x32_bf16(aR1,
                *(const bf16x8*)(sgp + ((size_t)(4 + q) * 64 + p0 + nn) * 8), acc, 0, 0, 0);
        if (p0 + nn < np) {
            #pragma unroll
            for (int r = 0; r < 4; ++r) {
                int ch = wv * 16 + q * 4 + r;
                dst[(size_t)(n * C + ch) * dst_stride + l0 + p0 + nn]
                    = acc[r] + sres[ch * 65 + p0 + nn];
            }
        }
    }

    const int sbase = Lout - OSIZE;
    for (int item = t; item < 8 * TILE; item += 256) {
        int p  = item & 63;
        int kg = item >> 6;
        int l  = l0 + p;
        if (l >= sbase && l < Lout) {
            *(bf16x8*)(gout + (((size_t)n * 8 + kg) * OSIZE + (l - sbase)) * 8)
                = *(const bf16x8*)(sgp + ((size_t)kg * 64 + p) * 8);
        }
    }
}

// ---- skip = sum over G layers of Ws@g ; ST=64, ring-3, reg-pipelined A ----
__global__ __launch_bounds__(256, 4) void skip_gemm(
    const __bf16* __restrict__ g,     // [G][NBATCH][8][OSIZE][8]
    const __bf16* __restrict__ Wsm,   // [16][128][64]
    float* __restrict__ skip,         // [NBATCH][128][OSIZE]
    int G, int lybase, int init)
{
    __shared__ __bf16 Bb[3][8][SST][8];   // 24 KB ring
    const int n  = blockIdx.y;
    const int l0 = blockIdx.x * SST;
    const int t  = threadIdx.x;
    const int lane = t & 63;
    const int wv   = __builtin_amdgcn_readfirstlane(t >> 6);
    const int q = lane >> 4, nn = lane & 15;

    f32x4 acc[2][4];
    #pragma unroll
    for (int mt = 0; mt < 2; ++mt)
        #pragma unroll
        for (int nt = 0; nt < 4; ++nt) acc[mt][nt] = (f32x4){0.f, 0.f, 0.f, 0.f};

    // stage K-tile gi (8 KB/block; 2 global_load_lds x 16B per wave)
    auto stage = [&](int buf, int gi) {
        const __bf16* gl = g + ((size_t)gi * NBATCH + n) * (size_t)8 * OSIZE * 8;
        #pragma unroll
        for (int j = 0; j < 2; ++j) {
            int kg = 2 * wv + j;
            const __bf16* srcp = gl + ((size_t)kg * OSIZE + l0) * 8 + (size_t)lane * 8;
            __builtin_amdgcn_global_load_lds(
                (const __attribute__((address_space(1))) void*)srcp,
                (__attribute__((address_space(3))) void*)&Bb[buf][kg][0][0],
                16, 0, 0);
        }
    };
    auto loadA = [&](int gi, bf16x8* A) {
        const __bf16* Wl = Wsm + (size_t)(lybase + gi) * SC * 64;
        A[0] = *(const bf16x8*)(Wl + (size_t)(wv * 32 +      nn) * 64 +      q * 8);
        A[1] = *(const bf16x8*)(Wl + (size_t)(wv * 32 +      nn) * 64 + 32 + q * 8);
        A[2] = *(const bf16x8*)(Wl + (size_t)(wv * 32 + 16 + nn) * 64 +      q * 8);
        A[3] = *(const bf16x8*)(Wl + (size_t)(wv * 32 + 16 + nn) * 64 + 32 + q * 8);
    };
    auto mfma16 = [&](const bf16x8* A, int cur) {
        #pragma unroll
        for (int ks = 0; ks < 2; ++ks) {
            #pragma unroll
            for (int nt = 0; nt < 4; ++nt) {
                bf16x8 b = *(const bf16x8*)&Bb[cur][ks * 4 + q][nt * 16 + nn][0];
                acc[0][nt] = __builtin_amdgcn_mfma_f32_16x16x32_bf16(
                                 A[ks], b, acc[0][nt], 0, 0, 0);
                acc[1][nt] = __builtin_amdgcn_mfma_f32_16x16x32_bf16(
                                 A[2 + ks], b, acc[1][nt], 0, 0, 0);
            }
        }
    };

    bf16x8 aA[4], aB[4];
    // prologue issue order: stage0(2), A0(4), stage1(2)
    stage(0, 0);
    loadA(0, aA);
    stage(1, G > 1 ? 1 : 0);

    for (int gi = 0; gi < G; gi += 2) {
        // ---- even half: tile gi (regs aA); prefetch A(gi+1)->aB, stage gi+2 ----
        asm volatile("s_waitcnt vmcnt(6)" ::: "memory");   // tile gi landed
        __builtin_amdgcn_s_barrier();
        __builtin_amdgcn_sched_barrier(0);
        loadA(gi + 1 < G ? gi + 1 : gi, aB);               // issued before stage
        stage((gi + 2) % 3, gi + 2 < G ? gi + 2 : G - 1);
        __builtin_amdgcn_sched_barrier(0);
        mfma16(aA, gi % 3);                                // A-wait leaves stages in flight
        __builtin_amdgcn_s_barrier();

        // ---- odd half: tile gi+1 (regs aB); prefetch A(gi+2)->aA, stage gi+3 ----
        asm volatile("s_waitcnt vmcnt(6)" ::: "memory");   // tile gi+1 landed
        __builtin_amdgcn_s_barrier();
        __builtin_amdgcn_sched_barrier(0);
        loadA(gi + 2 < G ? gi + 2 : gi, aA);
        stage((gi + 3) % 3, gi + 3 < G ? gi + 3 : G - 1);
        __builtin_amdgcn_sched_barrier(0);
        mfma16(aB, (gi + 1) % 3);
        __builtin_amdgcn_s_barrier();
    }

    // ---- epilogue: row-major store order (4x64B segments of a row back-to-back) ----
    #pragma unroll
    for (int mt = 0; mt < 2; ++mt)
        #pragma unroll
        for (int r = 0; r < 4; ++r) {
            int s = wv * 32 + mt * 16 + q * 4 + r;
            float* row = skip + ((size_t)n * SC + s) * OSIZE;
            #pragma unroll
            for (int nt = 0; nt < 4; ++nt) {
                int p = l0 + nt * 16 + nn;
                if (p < OSIZE) {
                    float v = acc[mt][nt][r];
                    row[p] = init ? v : (row[p] + v);
                }
            }
        }
}

extern "C" void kernel_launch(void* const* d_in, const int* in_sizes, int n_in,
                              void* d_out, int out_size, void* d_ws, size_t ws_size,
                              hipStream_t stream) {
    const float* x      = (const float*)d_in[0];
    const float* W_dil  = (const float*)d_in[1];
    const float* W_res  = (const float*)d_in[2];
    const float* W_skip = (const float*)d_in[3];

    float* out  = (float*)d_out;                        // [16][64][7682]
    float* skip = out + (size_t)NBATCH * C * OSIZE;     // [16][128][7682]

    float*  bufA = (float*)d_ws;
    float*  bufB = bufA + (size_t)NBATCH * C * L0;
    __bf16* Wdm  = (__bf16*)(bufB + (size_t)NBATCH * C * L0);
    __bf16* Wrm  = Wdm + 16 * 64 * 128;
    __bf16* Wsm  = Wrm + 16 * 64 * 64;
    __bf16* gst  = Wsm + 16 * 128 * 64;

    const size_t slotHW = (size_t)NBATCH * 8 * OSIZE * 8;   // halfwords per slot
    const int G = 8;

    pack_weights<<<1280, 256, 0, stream>>>(W_dil, W_res, W_skip, Wdm, Wrm, Wsm);

    // ---- stack A: fused epoch layers 0-4 (d=1..16) ----
    {
        int Lin = L0, Lf = Lin - 31;                    // 8161
        dim3 grid((Lf + 63) / 64, NBATCH);
        wavenet_epoch5<<<grid, 256, 0, stream>>>(
            x, Lin, bufA, Wdm, Wrm, gst, slotHW);
    }
    // singles: layers 5,6,7 (d=32,64,128)
    {
        const float* src = bufA; float* dsts[3] = {bufB, bufA, bufB};
        int Lin = L0 - 31;
        for (int k = 0; k < 3; ++k) {
            int i = 5 + k, d = 32 << k, Lout = Lin - d;
            int W = TILE + d;
            size_t smem = (size_t)128 * W + 64 * 65 * 4 + 8 * 64 * 8 * 2;
            dim3 grid((Lout + TILE - 1) / TILE, NBATCH);
            wavenet_layer_mfma<<<grid, 256, smem, stream>>>(
                src, L0, Lin, dsts[k], L0,
                Wdm + (size_t)i * 64 * 128, Wrm + (size_t)i * 64 * 64,
                gst + (size_t)(i % G) * slotHW, d);
            src = dsts[k]; Lin = Lout;
        }
    }
    {   // skip over layers 0..7
        dim3 sgrid((OSIZE + SST - 1) / SST, NBATCH);
        skip_gemm<<<sgrid, 256, 0, stream>>>(gst, Wsm, skip, G, 0, 1);
    }

    // ---- stack B: fused epoch layers 8-12 ----
    {
        int Lin = L0 - 255;                              // 7937
        int Lf = Lin - 31;                               // 7906
        dim3 grid((Lf + 63) / 64, NBATCH);
        wavenet_epoch5<<<grid, 256, 0, stream>>>(
            bufB, Lin, bufA,
            Wdm + (size_t)8 * 64 * 128, Wrm + (size_t)8 * 64 * 64,
            gst, slotHW);                                // slots (8..12)%8 = 0..4
    }
    // singles: layers 13,14 (-> bufs), 15 (d=128 -> out, stride OSIZE)
    {
        const float* src = bufA;
        int Lin = L0 - 255 - 31;                         // 7906
        float* dsts[3] = {bufB, bufA, out};
        int strides[3] = {L0, L0, OSIZE};
        for (int k = 0; k < 3; ++k) {
            int i = 13 + k, d = 32 << k, Lout = Lin - d;
            int W = TILE + d;
            size_t smem = (size_t)128 * W + 64 * 65 * 4 + 8 * 64 * 8 * 2;
            dim3 grid((Lout + TILE - 1) / TILE, NBATCH);
            wavenet_layer_mfma<<<grid, 256, smem, stream>>>(
                src, L0, Lin, dsts[k], strides[k],
                Wdm + (size_t)i * 64 * 128, Wrm + (size_t)i * 64 * 64,
                gst + (size_t)(i % G) * slotHW, d);
            src = dsts[k]; Lin = Lout;
        }
    }
    {   // skip over layers 8..15
        dim3 sgrid((OSIZE + SST - 1) / SST, NBATCH);
        skip_gemm<<<sgrid, 256, 0, stream>>>(gst, Wsm, skip, G, 8, 0);
    }
}

// Round 12
// 543.796 us; speedup vs baseline: 1.2486x; 1.0048x over previous
//
#include <hip/hip_runtime.h>

// WaveNet residual stack — round 21: epoch vmcnt-free per-layer barriers.
//  r20 WIN (553.7->546.4): row-major skip stores killed write amplification
//  (WRITE 84->67 MB), skip 93 µs. Buckets now: epochs ~185, skips ~186,
//  singles ~150. This round: the epoch's 10 per-layer __syncthreads each
//  compile to s_waitcnt vmcnt(0) lgkmcnt(0) + s_barrier — draining the
//  PREVIOUS layer's global g-stores on every layer. Those barriers only
//  need to order LDS (sgp/sxp); g-stores have no in-kernel reader. Replace
//  with {sched_barrier; s_waitcnt lgkmcnt(0); s_barrier; sched_barrier}
//  (rule #18: fence needed so hipcc can't hoist). Zero register cost —
//  the r19 gbuf attempt at the same mechanism minus its spill.
//  skip_gemm (r20), singles (r9), schedule: verbatim.
// MFMA layouts (HW-verified): A[m=lane&15][k=quad*8+j], B[k=quad*8+j][n=lane&15],
// C/D col=lane&15 row=quad*4+reg.

#define NBATCH 16
#define C 64
#define SC 128
#define L0 8192
#define OSIZE 7682
#define TILE 64
#define SST 64

typedef __bf16 bf16x8 __attribute__((ext_vector_type(8)));
typedef __bf16 bf16x4 __attribute__((ext_vector_type(4)));
typedef float  f32x4  __attribute__((ext_vector_type(4)));

__device__ __forceinline__ void lds_barrier() {
    __builtin_amdgcn_sched_barrier(0);
    asm volatile("s_waitcnt lgkmcnt(0)" ::: "memory");
    __builtin_amdgcn_s_barrier();
    __builtin_amdgcn_sched_barrier(0);
}

// ---- pre-pass: pack weights to bf16, k-contiguous MFMA A-layout ----
__global__ __launch_bounds__(256) void pack_weights(
    const float* __restrict__ Wd, const float* __restrict__ Wr,
    const float* __restrict__ Ws,
    __bf16* __restrict__ Wdm, __bf16* __restrict__ Wrm, __bf16* __restrict__ Wsm)
{
    int idx = blockIdx.x * 256 + threadIdx.x;
    if (idx < 131072) {                       // Wdm[ly][o][kp]: kp<64 tap0, else tap1
        int kp = idx & 127, o = (idx >> 7) & 63, ly = idx >> 13;
        int k = kp & 63, tap = kp >> 6;
        Wdm[idx] = (__bf16)Wd[(((ly * 64 + o) * 64 + k) << 1) + tap];
    } else if (idx < 196608) {                // Wrm[ly][o][k]
        int j = idx - 131072;
        Wrm[j] = (__bf16)Wr[j];
    } else if (idx < 327680) {                // Wsm[ly][s][k]
        int j = idx - 196608;
        Wsm[j] = (__bf16)Ws[j];
    }
}

// ---- fused 5-layer epoch (d=1,2,4,8,16), absolute right-tap coords ----
__global__ __launch_bounds__(256, 3) void wavenet_epoch5(
    const float* __restrict__ src, int Lin,    // stride L0
    float* __restrict__ dst,                   // stride L0, length Lin-31
    const __bf16* __restrict__ Wdm,            // 5 x [64][128] from base layer
    const __bf16* __restrict__ Wrm,            // 5 x [64][64]
    __bf16* __restrict__ gst, size_t slotHW)   // slots l = 0..4
{
    __shared__ __bf16 sxp[8][112][8];   // storage pp = p+16; pp<16 = zero pad
    __shared__ __bf16 sgp[8][96][8];    // gate out at p in [0,96)

    const int Lf = Lin - 31;
    const int n  = blockIdx.y;
    const int o0 = blockIdx.x * 64;     // own final cols [o0, o0+64) (left-aligned)
    if (o0 >= Lf) return;

    const int t    = threadIdx.x;
    const int lane = t & 63;
    const int wv   = t >> 6;
    const int q    = lane >> 4;
    const int nn   = lane & 15;
    const int kgw  = 2 * wv + (q >> 1);
    const int hf4  = (q & 1) * 4;

    // ---- initial stage: src cols [o0, o0+96) -> xs regs + bf16 LDS (pp=p+16) ----
    f32x4 xs[6];                            // ch = wv*16+q*4+r, p = nt*16+nn
    const float* base = src + (size_t)(n * C + wv * 16 + q * 4) * L0 + o0;
    #pragma unroll
    for (int nt = 0; nt < 6; ++nt) {
        int p = nt * 16 + nn;
        bool inb = (o0 + p) < Lin;
        #pragma unroll
        for (int r = 0; r < 4; ++r)
            xs[nt][r] = inb ? base[(size_t)r * L0 + p] : 0.f;
        bf16x4 v;
        #pragma unroll
        for (int r = 0; r < 4; ++r) v[r] = (__bf16)xs[nt][r];
        *(bf16x4*)(&sxp[0][0][0] + ((size_t)kgw * 112 + 16 + p) * 8 + hf4) = v;
    }
    {   // zero the left pad pp in [0,16)
        bf16x4 z = {(__bf16)0.f, (__bf16)0.f, (__bf16)0.f, (__bf16)0.f};
        *(bf16x4*)(&sxp[0][0][0] + ((size_t)kgw * 112 + nn) * 8 + hf4) = z;
    }
    lds_barrier();   // staged global loads consumed by data-dep; LDS-only order

    #pragma unroll 1
    for (int l = 0; l < 5; ++l) {
        const int d = 1 << l;

        // ---- conv+gate: gate(p) = f(x(p-d), x(p))  [right-tap aligned] ----
        const __bf16* aw = Wdm + ((size_t)l * 64 + wv * 16 + nn) * 128 + q * 8;
        bf16x8 aW0 = *(const bf16x8*)(aw);        // tap0 (left), k 0..31
        bf16x8 aW1 = *(const bf16x8*)(aw + 32);   // tap0, k 32..63
        bf16x8 aW2 = *(const bf16x8*)(aw + 64);   // tap1 (right), k 0..31
        bf16x8 aW3 = *(const bf16x8*)(aw + 96);   // tap1, k 32..63
        #pragma unroll
        for (int nt = 0; nt < 6; ++nt) {
            int p = nt * 16 + nn;
            f32x4 acc = {0.f, 0.f, 0.f, 0.f};
            acc = __builtin_amdgcn_mfma_f32_16x16x32_bf16(aW0,
                    *(const bf16x8*)(&sxp[0][0][0] + ((size_t)(q    ) * 112 + 16 + p - d) * 8), acc, 0, 0, 0);
            acc = __builtin_amdgcn_mfma_f32_16x16x32_bf16(aW1,
                    *(const bf16x8*)(&sxp[0][0][0] + ((size_t)(4 + q) * 112 + 16 + p - d) * 8), acc, 0, 0, 0);
            acc = __builtin_amdgcn_mfma_f32_16x16x32_bf16(aW2,
                    *(const bf16x8*)(&sxp[0][0][0] + ((size_t)(q    ) * 112 + 16 + p    ) * 8), acc, 0, 0, 0);
            acc = __builtin_amdgcn_mfma_f32_16x16x32_bf16(aW3,
                    *(const bf16x8*)(&sxp[0][0][0] + ((size_t)(4 + q) * 112 + 16 + p    ) * 8), acc, 0, 0, 0);
            bf16x4 gv;
            #pragma unroll
            for (int r = 0; r < 4; ++r) {
                float y = fminf(fmaxf(acc[r], -20.f), 20.f);
                float u = __expf(y);
                gv[r] = (__bf16)(u * (u - 1.f) / fmaf(u, u, 1.f));
            }
            *(bf16x4*)(&sgp[0][0][0] + ((size_t)kgw * 96 + p) * 8 + hf4) = gv;
        }
        lds_barrier();   // sgp visible; conv's sxp reads done. g-stores stay in flight.

        // ---- res: xs(p) = Wr@g(p) + xs(p)  [same absolute col] ----
        const __bf16* ar = Wrm + ((size_t)l * 64 + wv * 16 + nn) * 64 + q * 8;
        bf16x8 aR0 = *(const bf16x8*)ar;
        bf16x8 aR1 = *(const bf16x8*)(ar + 32);
        #pragma unroll
        for (int nt = 0; nt < 6; ++nt) {
            int p = nt * 16 + nn;
            bf16x8 b0 = *(const bf16x8*)(&sgp[0][0][0] + ((size_t)(q    ) * 96 + p) * 8);
            bf16x8 b1 = *(const bf16x8*)(&sgp[0][0][0] + ((size_t)(4 + q) * 96 + p) * 8);
            xs[nt] = __builtin_amdgcn_mfma_f32_16x16x32_bf16(aR1, b1,
                     __builtin_amdgcn_mfma_f32_16x16x32_bf16(aR0, b0, xs[nt], 0, 0, 0),
                     0, 0, 0);
            bf16x4 v;
            #pragma unroll
            for (int r = 0; r < 4; ++r) v[r] = (__bf16)xs[nt][r];
            *(bf16x4*)(&sxp[0][0][0] + ((size_t)kgw * 112 + 16 + p) * 8 + hf4) = v;
        }

        // ---- g window write: left index i = o0+p-Dl, window [Ll-OSIZE, Ll) ----
        const int Dl = (2 << l) - 1;           // cumulative dilation through l
        const int Ll = Lin - Dl;
        const int sb = Ll - OSIZE;             // >= 224 for all stacks/layers
        __bf16* gsl = gst + (size_t)l * slotHW;
        for (int item = t; item < 8 * 64; item += 256) {
            int p  = 31 + (item & 63);         // own range [31,95)
            int kg = item >> 6;
            int i  = o0 + p - Dl;
            if (i >= sb && i < Ll) {
                *(bf16x8*)(gsl + (((size_t)n * 8 + kg) * OSIZE + (i - sb)) * 8)
                    = *(const bf16x8*)(&sgp[0][0][0] + ((size_t)kg * 96 + p) * 8);
            }
        }
        lds_barrier();   // sxp refresh visible; sgp reads done. No vmcnt drain.
    }

    // ---- write epoch-final stream: dst col i = o0 + p - 31, p in [31,95) ----
    #pragma unroll
    for (int nt = 1; nt < 6; ++nt) {
        int p = nt * 16 + nn;
        if (p >= 31 && p < 95) {
            int i = o0 + p - 31;
            if (i < Lf) {
                #pragma unroll
                for (int r = 0; r < 4; ++r)
                    dst[(size_t)(n * C + wv * 16 + q * 4 + r) * L0 + i] = xs[nt][r];
            }
        }
    }
}

// ---- per-layer: conv(MFMA) + gate + res(MFMA) + g window out (r9-verbatim) ----
__global__ __launch_bounds__(256) void wavenet_layer_mfma(
    const float* __restrict__ src, int src_stride, int Lin,
    float* __restrict__ dst, int dst_stride,
    const __bf16* __restrict__ Wdm,   // [64][128]
    const __bf16* __restrict__ Wrm,   // [64][64]
    __bf16* __restrict__ gout,        // [NBATCH][8][OSIZE][8] this layer's slot
    int d)
{
    extern __shared__ char smem_raw[];
    const int W    = TILE + d;
    const int Lout = Lin - d;
    const int n  = blockIdx.y;
    const int l0 = blockIdx.x * TILE;
    if (l0 >= Lout) return;
    const int np = min(TILE, Lout - l0);

    __bf16* sxp  = (__bf16*)smem_raw;                          // [8][W][8] k-packed
    float*  sres = (float*)(smem_raw + (size_t)8 * W * 8 * 2); // [64][65] fp32
    __bf16* sgp  = (__bf16*)(sres + 64 * 65);                  // [8][64][8] k-packed

    const int t    = threadIdx.x;
    const int lane = t & 63;
    const int wv   = t >> 6;
    const int q    = lane >> 4;
    const int nn   = lane & 15;

    for (int item = t; item < 8 * W; item += 256) {
        int kg = item / W;
        int p  = item % W;
        bool inb = (l0 + p) < Lin;
        const float* col = src + (size_t)(n * C + kg * 8) * src_stride + l0 + p;
        float v[8];
        #pragma unroll
        for (int j = 0; j < 8; ++j) v[j] = inb ? col[(size_t)j * src_stride] : 0.f;
        bf16x8 bv;
        #pragma unroll
        for (int j = 0; j < 8; ++j) bv[j] = (__bf16)v[j];
        *(bf16x8*)(sxp + ((size_t)kg * W + p) * 8) = bv;
        int pr = p - d;
        if (pr >= 0 && pr < TILE) {
            #pragma unroll
            for (int j = 0; j < 8; ++j) sres[(kg * 8 + j) * 65 + pr] = v[j];
        }
    }
    __syncthreads();

    const __bf16* arow = Wdm + (size_t)(wv * 16 + nn) * 128 + q * 8;
    bf16x8 aW[4];
    #pragma unroll
    for (int ks = 0; ks < 4; ++ks) aW[ks] = *(const bf16x8*)(arow + ks * 32);

    #pragma unroll
    for (int nt = 0; nt < 4; ++nt) {
        int p0 = nt * 16;
        f32x4 acc = {0.f, 0.f, 0.f, 0.f};
        acc = __builtin_amdgcn_mfma_f32_16x16x32_bf16(aW[0],
                *(const bf16x8*)(sxp + ((size_t)(q    ) * W + p0 + nn    ) * 8), acc, 0, 0, 0);
        acc = __builtin_amdgcn_mfma_f32_16x16x32_bf16(aW[1],
                *(const bf16x8*)(sxp + ((size_t)(4 + q) * W + p0 + nn    ) * 8), acc, 0, 0, 0);
        acc = __builtin_amdgcn_mfma_f32_16x16x32_bf16(aW[2],
                *(const bf16x8*)(sxp + ((size_t)(q    ) * W + p0 + nn + d) * 8), acc, 0, 0, 0);
        acc = __builtin_amdgcn_mfma_f32_16x16x32_bf16(aW[3],
                *(const bf16x8*)(sxp + ((size_t)(4 + q) * W + p0 + nn + d) * 8), acc, 0, 0, 0);
        bf16x4 gv;
        #pragma unroll
        for (int r = 0; r < 4; ++r) {
            float y = fminf(fmaxf(acc[r], -20.f), 20.f);
            float u = __expf(y);
            gv[r] = (__bf16)(u * (u - 1.f) / fmaf(u, u, 1.f));
        }
        *(bf16x4*)(sgp + ((size_t)(2 * wv + (q >> 1)) * 64 + p0 + nn) * 8 + (q & 1) * 4) = gv;
    }
    __syncthreads();

    const __bf16* rrow = Wrm + (size_t)(wv * 16 + nn) * 64 + q * 8;
    bf16x8 aR0 = *(const bf16x8*)rrow;
    bf16x8 aR1 = *(const bf16x8*)(rrow + 32);
    #pragma unroll
    for (int nt = 0; nt < 4; ++nt) {
        int p0 = nt * 16;
        f32x4 acc = {0.f, 0.f, 0.f, 0.f};
        acc = __builtin_amdgcn_mfma_f32_16x16x32_bf16(aR0,
                *(const bf16x8*)(sgp + ((size_t)(q    ) * 64 + p0 + nn) * 8), acc, 0, 0, 0);
        acc = __builtin_amdgcn_mfma_f32_16x16x32_bf16(aR1,
                *(const bf16x8*)(sgp + ((size_t)(4 + q) * 64 + p0 + nn) * 8), acc, 0, 0, 0);
        if (p0 + nn < np) {
            #pragma unroll
            for (int r = 0; r < 4; ++r) {
                int ch = wv * 16 + q * 4 + r;
                dst[(size_t)(n * C + ch) * dst_stride + l0 + p0 + nn]
                    = acc[r] + sres[ch * 65 + p0 + nn];
            }
        }
    }

    const int sbase = Lout - OSIZE;
    for (int item = t; item < 8 * TILE; item += 256) {
        int p  = item & 63;
        int kg = item >> 6;
        int l  = l0 + p;
        if (l >= sbase && l < Lout) {
            *(bf16x8*)(gout + (((size_t)n * 8 + kg) * OSIZE + (l - sbase)) * 8)
                = *(const bf16x8*)(sgp + ((size_t)kg * 64 + p) * 8);
        }
    }
}

// ---- skip = sum over G layers of Ws@g ; ST=64, ring-3, reg-pipelined A (r20) ----
__global__ __launch_bounds__(256, 4) void skip_gemm(
    const __bf16* __restrict__ g,     // [G][NBATCH][8][OSIZE][8]
    const __bf16* __restrict__ Wsm,   // [16][128][64]
    float* __restrict__ skip,         // [NBATCH][128][OSIZE]
    int G, int lybase, int init)
{
    __shared__ __bf16 Bb[3][8][SST][8];   // 24 KB ring
    const int n  = blockIdx.y;
    const int l0 = blockIdx.x * SST;
    const int t  = threadIdx.x;
    const int lane = t & 63;
    const int wv   = __builtin_amdgcn_readfirstlane(t >> 6);
    const int q = lane >> 4, nn = lane & 15;

    f32x4 acc[2][4];
    #pragma unroll
    for (int mt = 0; mt < 2; ++mt)
        #pragma unroll
        for (int nt = 0; nt < 4; ++nt) acc[mt][nt] = (f32x4){0.f, 0.f, 0.f, 0.f};

    // stage K-tile gi (8 KB/block; 2 global_load_lds x 16B per wave)
    auto stage = [&](int buf, int gi) {
        const __bf16* gl = g + ((size_t)gi * NBATCH + n) * (size_t)8 * OSIZE * 8;
        #pragma unroll
        for (int j = 0; j < 2; ++j) {
            int kg = 2 * wv + j;
            const __bf16* srcp = gl + ((size_t)kg * OSIZE + l0) * 8 + (size_t)lane * 8;
            __builtin_amdgcn_global_load_lds(
                (const __attribute__((address_space(1))) void*)srcp,
                (__attribute__((address_space(3))) void*)&Bb[buf][kg][0][0],
                16, 0, 0);
        }
    };
    auto loadA = [&](int gi, bf16x8* A) {
        const __bf16* Wl = Wsm + (size_t)(lybase + gi) * SC * 64;
        A[0] = *(const bf16x8*)(Wl + (size_t)(wv * 32 +      nn) * 64 +      q * 8);
        A[1] = *(const bf16x8*)(Wl + (size_t)(wv * 32 +      nn) * 64 + 32 + q * 8);
        A[2] = *(const bf16x8*)(Wl + (size_t)(wv * 32 + 16 + nn) * 64 +      q * 8);
        A[3] = *(const bf16x8*)(Wl + (size_t)(wv * 32 + 16 + nn) * 64 + 32 + q * 8);
    };
    auto mfma16 = [&](const bf16x8* A, int cur) {
        #pragma unroll
        for (int ks = 0; ks < 2; ++ks) {
            #pragma unroll
            for (int nt = 0; nt < 4; ++nt) {
                bf16x8 b = *(const bf16x8*)&Bb[cur][ks * 4 + q][nt * 16 + nn][0];
                acc[0][nt] = __builtin_amdgcn_mfma_f32_16x16x32_bf16(
                                 A[ks], b, acc[0][nt], 0, 0, 0);
                acc[1][nt] = __builtin_amdgcn_mfma_f32_16x16x32_bf16(
                                 A[2 + ks], b, acc[1][nt], 0, 0, 0);
            }
        }
    };

    bf16x8 aA[4], aB[4];
    // prologue issue order: stage0(2), A0(4), stage1(2)
    stage(0, 0);
    loadA(0, aA);
    stage(1, G > 1 ? 1 : 0);

    for (int gi = 0; gi < G; gi += 2) {
        // ---- even half: tile gi (regs aA); prefetch A(gi+1)->aB, stage gi+2 ----
        asm volatile("s_waitcnt vmcnt(6)" ::: "memory");   // tile gi landed
        __builtin_amdgcn_s_barrier();
        __builtin_amdgcn_sched_barrier(0);
        loadA(gi + 1 < G ? gi + 1 : gi, aB);               // issued before stage
        stage((gi + 2) % 3, gi + 2 < G ? gi + 2 : G - 1);
        __builtin_amdgcn_sched_barrier(0);
        mfma16(aA, gi % 3);                                // A-wait leaves stages in flight
        __builtin_amdgcn_s_barrier();

        // ---- odd half: tile gi+1 (regs aB); prefetch A(gi+2)->aA, stage gi+3 ----
        asm volatile("s_waitcnt vmcnt(6)" ::: "memory");   // tile gi+1 landed
        __builtin_amdgcn_s_barrier();
        __builtin_amdgcn_sched_barrier(0);
        loadA(gi + 2 < G ? gi + 2 : gi, aA);
        stage((gi + 3) % 3, gi + 3 < G ? gi + 3 : G - 1);
        __builtin_amdgcn_sched_barrier(0);
        mfma16(aB, (gi + 1) % 3);
        __builtin_amdgcn_s_barrier();
    }

    // ---- epilogue: row-major store order (4x64B segments of a row back-to-back) ----
    #pragma unroll
    for (int mt = 0; mt < 2; ++mt)
        #pragma unroll
        for (int r = 0; r < 4; ++r) {
            int s = wv * 32 + mt * 16 + q * 4 + r;
            float* row = skip + ((size_t)n * SC + s) * OSIZE;
            #pragma unroll
            for (int nt = 0; nt < 4; ++nt) {
                int p = l0 + nt * 16 + nn;
                if (p < OSIZE) {
                    float v = acc[mt][nt][r];
                    row[p] = init ? v : (row[p] + v);
                }
            }
        }
}

extern "C" void kernel_launch(void* const* d_in, const int* in_sizes, int n_in,
                              void* d_out, int out_size, void* d_ws, size_t ws_size,
                              hipStream_t stream) {
    const float* x      = (const float*)d_in[0];
    const float* W_dil  = (const float*)d_in[1];
    const float* W_res  = (const float*)d_in[2];
    const float* W_skip = (const float*)d_in[3];

    float* out  = (float*)d_out;                        // [16][64][7682]
    float* skip = out + (size_t)NBATCH * C * OSIZE;     // [16][128][7682]

    float*  bufA = (float*)d_ws;
    float*  bufB = bufA + (size_t)NBATCH * C * L0;
    __bf16* Wdm  = (__bf16*)(bufB + (size_t)NBATCH * C * L0);
    __bf16* Wrm  = Wdm + 16 * 64 * 128;
    __bf16* Wsm  = Wrm + 16 * 64 * 64;
    __bf16* gst  = Wsm + 16 * 128 * 64;

    const size_t slotHW = (size_t)NBATCH * 8 * OSIZE * 8;   // halfwords per slot
    const int G = 8;

    pack_weights<<<1280, 256, 0, stream>>>(W_dil, W_res, W_skip, Wdm, Wrm, Wsm);

    // ---- stack A: fused epoch layers 0-4 (d=1..16) ----
    {
        int Lin = L0, Lf = Lin - 31;                    // 8161
        dim3 grid((Lf + 63) / 64, NBATCH);
        wavenet_epoch5<<<grid, 256, 0, stream>>>(
            x, Lin, bufA, Wdm, Wrm, gst, slotHW);
    }
    // singles: layers 5,6,7 (d=32,64,128)
    {
        const float* src = bufA; float* dsts[3] = {bufB, bufA, bufB};
        int Lin = L0 - 31;
        for (int k = 0; k < 3; ++k) {
            int i = 5 + k, d = 32 << k, Lout = Lin - d;
            int W = TILE + d;
            size_t smem = (size_t)128 * W + 64 * 65 * 4 + 8 * 64 * 8 * 2;
            dim3 grid((Lout + TILE - 1) / TILE, NBATCH);
            wavenet_layer_mfma<<<grid, 256, smem, stream>>>(
                src, L0, Lin, dsts[k], L0,
                Wdm + (size_t)i * 64 * 128, Wrm + (size_t)i * 64 * 64,
                gst + (size_t)(i % G) * slotHW, d);
            src = dsts[k]; Lin = Lout;
        }
    }
    {   // skip over layers 0..7
        dim3 sgrid((OSIZE + SST - 1) / SST, NBATCH);
        skip_gemm<<<sgrid, 256, 0, stream>>>(gst, Wsm, skip, G, 0, 1);
    }

    // ---- stack B: fused epoch layers 8-12 ----
    {
        int Lin = L0 - 255;                              // 7937
        int Lf = Lin - 31;                               // 7906
        dim3 grid((Lf + 63) / 64, NBATCH);
        wavenet_epoch5<<<grid, 256, 0, stream>>>(
            bufB, Lin, bufA,
            Wdm + (size_t)8 * 64 * 128, Wrm + (size_t)8 * 64 * 64,
            gst, slotHW);                                // slots (8..12)%8 = 0..4
    }
    // singles: layers 13,14 (-> bufs), 15 (d=128 -> out, stride OSIZE)
    {
        const float* src = bufA;
        int Lin = L0 - 255 - 31;                         // 7906
        float* dsts[3] = {bufB, bufA, out};
        int strides[3] = {L0, L0, OSIZE};
        for (int k = 0; k < 3; ++k) {
            int i = 13 + k, d = 32 << k, Lout = Lin - d;
            int W = TILE + d;
            size_t smem = (size_t)128 * W + 64 * 65 * 4 + 8 * 64 * 8 * 2;
            dim3 grid((Lout + TILE - 1) / TILE, NBATCH);
            wavenet_layer_mfma<<<grid, 256, smem, stream>>>(
                src, L0, Lin, dsts[k], strides[k],
                Wdm + (size_t)i * 64 * 128, Wrm + (size_t)i * 64 * 64,
                gst + (size_t)(i % G) * slotHW, d);
            src = dsts[k]; Lin = Lout;
        }
    }
    {   // skip over layers 8..15
        dim3 sgrid((OSIZE + SST - 1) / SST, NBATCH);
        skip_gemm<<<sgrid, 256, 0, stream>>>(gst, Wsm, skip, G, 8, 0);
    }
}